// Round 5
// baseline (427.918 us; speedup 1.0000x reference)
//
#include <hip/hip_runtime.h>
#include <math.h>

#define NQ 40000
#define DIM 256
#define NH 8
#define NP 6
#define HD 32
#define GH 200
#define GW 200
#define TS 8
#define TNX 25
#define NT 625

typedef short bf16x8 __attribute__((ext_vector_type(8)));
typedef float f32x4 __attribute__((ext_vector_type(4)));

__device__ __forceinline__ unsigned short f2bf(float f) {
    unsigned int u = __builtin_bit_cast(unsigned int, f);
    u += 0x7fffu + ((u >> 16) & 1u);
    return (unsigned short)(u >> 16);
}
__device__ __forceinline__ float bf2f(unsigned short h) {
    return __builtin_bit_cast(float, ((unsigned int)h) << 16);
}
__device__ __forceinline__ bf16x8 pack8(const float4& a, const float4& b) {
    bf16x8 o;
    o[0] = (short)f2bf(a.x); o[1] = (short)f2bf(a.y);
    o[2] = (short)f2bf(a.z); o[3] = (short)f2bf(a.w);
    o[4] = (short)f2bf(b.x); o[5] = (short)f2bf(b.y);
    o[6] = (short)f2bf(b.z); o[7] = (short)f2bf(b.w);
    return o;
}

// ---------------------------------------------------------------------------
// Weight prep: transpose K x N fp32 -> [N][K] bf16 rows into Bt.
// Row offsets: Wval 0, Woff 256, Wattn 352, Wout 400, W1 656, W2 912.
// Also zeroes the sort histogram and packs bias_oa.
// ---------------------------------------------------------------------------
__global__ void __launch_bounds__(256)
wtrans_kernel(const float* __restrict__ Wval, const float* __restrict__ Woff,
              const float* __restrict__ Wattn, const float* __restrict__ Wout,
              const float* __restrict__ W1, const float* __restrict__ W2,
              const float* __restrict__ b_off, const float* __restrict__ b_attn,
              unsigned short* __restrict__ Bt, float* __restrict__ bias_oa,
              int* __restrict__ hist) {
    __shared__ float T[64][65];
    const int m = blockIdx.z;
    const float* src; int N; int dr0;
    if (m == 0)      { src = Wval;  N = 256; dr0 = 0; }
    else if (m == 1) { src = Woff;  N = 96;  dr0 = 256; }
    else if (m == 2) { src = Wattn; N = 48;  dr0 = 352; }
    else if (m == 3) { src = Wout;  N = 256; dr0 = 400; }
    else if (m == 4) { src = W1;    N = 256; dr0 = 656; }
    else             { src = W2;    N = 256; dr0 = 912; }

    if (m == 1 && blockIdx.x == 0 && blockIdx.y == 0 && threadIdx.x < 144)
        bias_oa[threadIdx.x] = threadIdx.x < 96 ? b_off[threadIdx.x]
                                                : b_attn[threadIdx.x - 96];
    if (m == 0 && blockIdx.y == 0) {
        const int i = blockIdx.x * 256 + threadIdx.x;
        if (i < NT) hist[i] = 0;
    }

    const int n0 = blockIdx.x * 64, k0 = blockIdx.y * 64;
    if (n0 >= N) return;
    const int col = threadIdx.x & 63, rg = threadIdx.x >> 6;
#pragma unroll
    for (int i = 0; i < 16; ++i) {
        const int r = rg + 4 * i;
        T[r][col] = (n0 + col < N) ? src[(size_t)(k0 + r) * N + n0 + col] : 0.0f;
    }
    __syncthreads();
#pragma unroll
    for (int i = 0; i < 16; ++i) {
        const int nl = rg + 4 * i;
        if (n0 + nl < N)
            Bt[(size_t)(dr0 + n0 + nl) * 256 + k0 + col] = f2bf(T[col][nl]);
    }
}

// ---------------------------------------------------------------------------
// Query spatial counting sort by 8x8-cell tile.
// ---------------------------------------------------------------------------
__device__ __forceinline__ int tile_of(const float* rp, int q) {
    const float rx = rp[q * 2 + 0] * (float)GW;
    const float ry = rp[q * 2 + 1] * (float)GH;
    const int tx = min(max((int)(rx * (1.0f / TS)), 0), TNX - 1);
    const int ty = min(max((int)(ry * (1.0f / TS)), 0), TNX - 1);
    return ty * TNX + tx;
}

__global__ void __launch_bounds__(256)
sort_hist(const float* __restrict__ rp, int* __restrict__ hist) {
    const int q = blockIdx.x * 256 + threadIdx.x;
    if (q >= NQ) return;
    atomicAdd(&hist[tile_of(rp, q)], 1);
}

__global__ void __launch_bounds__(64)
sort_scan(const int* __restrict__ hist, int* __restrict__ cursor) {
    const int lane = threadIdx.x;
    int loc[10]; int t = 0;
#pragma unroll
    for (int j = 0; j < 10; ++j) {
        const int idx = lane * 10 + j;
        loc[j] = t;
        t += (idx < NT) ? hist[idx] : 0;
    }
    int s = t;
#pragma unroll
    for (int o = 1; o < 64; o <<= 1) {
        const int u = __shfl_up(s, o);
        if (lane >= o) s += u;
    }
    const int ex = s - t;
#pragma unroll
    for (int j = 0; j < 10; ++j) {
        const int idx = lane * 10 + j;
        if (idx < NT) cursor[idx] = ex + loc[j];
    }
}

__global__ void __launch_bounds__(256)
sort_scatter(const float* __restrict__ rp, int* __restrict__ cursor,
             int* __restrict__ perm) {
    const int q = blockIdx.x * 256 + threadIdx.x;
    if (q >= NQ) return;
    const int pos = atomicAdd(&cursor[tile_of(rp, q)], 1);
    perm[pos] = q;
}

// ---------------------------------------------------------------------------
// gemm64: C[M,256] = epi(A[M,256] @ Bt[256,256]^T + bias)
// BM=64, BN=256 (full row per block), BK=32, 4 waves, LDS double-buffer.
// AF32: A is fp32, staged via regs + convert + ds_write (read once per block).
//       else A is bf16, staged via global_load_lds width-16.
// EPI: 1 = exact-gelu -> bf16, 2 = bf16,
//      3 = LN(x + res_fp32) -> bf16, 4 = LN(x + res_bf16) -> fp32.
// M multiple of 64.
// ---------------------------------------------------------------------------
template <int EPI, int AF32>
__global__ void __launch_bounds__(256)
gemm64(const void* __restrict__ Av, const unsigned short* __restrict__ Btw,
       const float* __restrict__ bias, const void* __restrict__ res,
       const float* __restrict__ lng, const float* __restrict__ lnb,
       void* __restrict__ C, int M) {
    __shared__ __align__(16) unsigned short As[2][64 * 32];
    __shared__ __align__(16) unsigned short Bs[2][256 * 32];
    __shared__ __align__(16) float red[64][4][2];

    const int tid = threadIdx.x, lane = tid & 63, wave = tid >> 6;
    const int quad = lane >> 4, l16 = lane & 15;
    const int bm0 = blockIdx.x * 64;
    const int r16 = lane >> 2, ch = (lane & 3) * 8;

    f32x4 acc[4][4] = {};

    const unsigned short* Ab = (const unsigned short*)Av;
    const float* Af = (const float*)Av;
    const int arow = tid >> 2, acol = (tid & 3) * 8;

    float4 a0, a1;
    auto loadA = [&](int kt) {
        const float* ap = Af + (size_t)(bm0 + arow) * 256 + kt * 32 + acol;
        a0 = *(const float4*)ap;
        a1 = *(const float4*)(ap + 4);
    };
    auto writeA = [&](int buf) {
        *(bf16x8*)&As[buf][arow * 32 + acol] = pack8(a0, a1);
    };
    auto stageA_lds = [&](int kt, int buf) {
        const unsigned short* gp =
            Ab + (size_t)(bm0 + wave * 16 + r16) * 256 + kt * 32 + ch;
        __builtin_amdgcn_global_load_lds(
            (const __attribute__((address_space(1))) void*)gp,
            (__attribute__((address_space(3))) void*)(&As[buf][wave * 16 * 32]),
            16, 0, 0);
    };
    auto stageB = [&](int kt, int buf) {
#pragma unroll
        for (int j = 0; j < 4; ++j) {
            const int rowbase = (wave * 4 + j) * 16;
            const unsigned short* gp =
                Btw + (size_t)(rowbase + r16) * 256 + kt * 32 + ch;
            __builtin_amdgcn_global_load_lds(
                (const __attribute__((address_space(1))) void*)gp,
                (__attribute__((address_space(3))) void*)(&Bs[buf][rowbase * 32]),
                16, 0, 0);
        }
    };

    if (AF32) { loadA(0); writeA(0); } else stageA_lds(0, 0);
    stageB(0, 0);
    __syncthreads();

    for (int kt = 0; kt < 8; ++kt) {
        const int cur = kt & 1;
        if (kt < 7) {
            stageB(kt + 1, 1 - cur);
            if (AF32) loadA(kt + 1); else stageA_lds(kt + 1, 1 - cur);
        }

        bf16x8 af[4], bw[4];
#pragma unroll
        for (int t = 0; t < 4; ++t) {
            af[t] = *(const bf16x8*)&As[cur][(t * 16 + l16) * 32 + quad * 8];
            bw[t] = *(const bf16x8*)&Bs[cur][(wave * 64 + t * 16 + l16) * 32 + quad * 8];
        }
#pragma unroll
        for (int tm = 0; tm < 4; ++tm)
#pragma unroll
            for (int tn = 0; tn < 4; ++tn)
                acc[tm][tn] = __builtin_amdgcn_mfma_f32_16x16x32_bf16(
                    af[tm], bw[tn], acc[tm][tn], 0, 0, 0);
        if (AF32 && kt < 7) writeA(1 - cur);
        __syncthreads();
    }

    // --- epilogue. C/D layout: col = lane&15, row = quad*4 + reg ---
    float bias4[4];
#pragma unroll
    for (int tn = 0; tn < 4; ++tn) bias4[tn] = bias[wave * 64 + tn * 16 + l16];

    if (EPI == 1 || EPI == 2) {
#pragma unroll
        for (int tm = 0; tm < 4; ++tm) {
            const int row0 = bm0 + tm * 16 + quad * 4;
#pragma unroll
            for (int tn = 0; tn < 4; ++tn) {
                const int col = wave * 64 + tn * 16 + l16;
#pragma unroll
                for (int r = 0; r < 4; ++r) {
                    float x = acc[tm][tn][r] + bias4[tn];
                    if (EPI == 1) x = 0.5f * x * (1.0f + erff(x * 0.70710678118654752f));
                    ((unsigned short*)C)[(size_t)(row0 + r) * 256 + col] = f2bf(x);
                }
            }
        }
        return;
    }

    // LN variants: add bias + residual, then row stats over 256 cols.
#pragma unroll
    for (int tm = 0; tm < 4; ++tm) {
#pragma unroll
        for (int r = 0; r < 4; ++r) {
            const size_t rb = (size_t)(bm0 + tm * 16 + quad * 4 + r) * 256;
#pragma unroll
            for (int tn = 0; tn < 4; ++tn) {
                const int col = wave * 64 + tn * 16 + l16;
                float e = acc[tm][tn][r] + bias4[tn];
                if (EPI == 3) e += ((const float*)res)[rb + col];
                else          e += bf2f(((const unsigned short*)res)[rb + col]);
                acc[tm][tn][r] = e;
            }
        }
    }
#pragma unroll
    for (int tm = 0; tm < 4; ++tm) {
#pragma unroll
        for (int r = 0; r < 4; ++r) {
            float s = 0.0f, sq = 0.0f;
#pragma unroll
            for (int tn = 0; tn < 4; ++tn) {
                const float e = acc[tm][tn][r];
                s += e; sq += e * e;
            }
#pragma unroll
            for (int o = 1; o < 16; o <<= 1) {
                s += __shfl_xor(s, o);
                sq += __shfl_xor(sq, o);
            }
            if (l16 == 0) {
                const int row = tm * 16 + quad * 4 + r;
                red[row][wave][0] = s;
                red[row][wave][1] = sq;
            }
        }
    }
    __syncthreads();

    float gv[4], bvv[4];
#pragma unroll
    for (int tn = 0; tn < 4; ++tn) {
        const int col = wave * 64 + tn * 16 + l16;
        gv[tn] = lng[col];
        bvv[tn] = lnb[col];
    }
#pragma unroll
    for (int tm = 0; tm < 4; ++tm) {
#pragma unroll
        for (int r = 0; r < 4; ++r) {
            const int row = tm * 16 + quad * 4 + r;
            const float4 p0 = *(const float4*)&red[row][0][0];
            const float4 p1 = *(const float4*)&red[row][2][0];
            const float sum = p0.x + p0.z + p1.x + p1.z;
            const float sumsq = p0.y + p0.w + p1.y + p1.w;
            const float mean = sum * (1.0f / 256.0f);
            const float var = sumsq * (1.0f / 256.0f) - mean * mean;
            const float rstd = rsqrtf(var + 1e-5f);
            const size_t rb = (size_t)(bm0 + row) * 256;
#pragma unroll
            for (int tn = 0; tn < 4; ++tn) {
                const int col = wave * 64 + tn * 16 + l16;
                const float o = (acc[tm][tn][r] - mean) * rstd * gv[tn] + bvv[tn];
                if (EPI == 3) ((unsigned short*)C)[rb + col] = f2bf(o);
                else          ((float*)C)[rb + col] = o;
            }
        }
    }
}

// ---------------------------------------------------------------------------
// offattn GEMM: fp32 A staged with in-kernel conversion; B bf16 via
// global_load_lds. 128x128 tile, grid (2, 313), N=144.
// ---------------------------------------------------------------------------
__global__ void __launch_bounds__(256)
gemm_bt(const float* __restrict__ A, const unsigned short* __restrict__ Btw,
        const float* __restrict__ bias, unsigned short* __restrict__ C,
        int M, int N, int ldc) {
    __shared__ __align__(16) unsigned short As[128 * 32];
    __shared__ __align__(16) unsigned short Bs[128 * 32];

    const int tid = threadIdx.x, lane = tid & 63, wave = tid >> 6;
    const int quad = lane >> 4, l16 = lane & 15;
    const int wm = wave >> 1, wn = wave & 1;
    const int bm0 = blockIdx.y * 128, bn0 = blockIdx.x * 128;

    f32x4 acc[4][4] = {};
    const int rl = lane >> 2;
    const int c8 = (lane & 3) * 8;
    const int rA = tid >> 1, cA = (tid & 1) * 16;

    for (int kt = 0; kt < 8; ++kt) {
        const int k0 = kt * 32;
        __syncthreads();
        // stage A: fp32 -> bf16, 16 elems/thread
        {
            const int ar = min(bm0 + rA, M - 1);
            const float* ap = A + (size_t)ar * 256 + k0 + cA;
            float4 x0 = *(const float4*)(ap);
            float4 x1 = *(const float4*)(ap + 4);
            float4 x2 = *(const float4*)(ap + 8);
            float4 x3 = *(const float4*)(ap + 12);
            *(bf16x8*)&As[rA * 32 + cA]     = pack8(x0, x1);
            *(bf16x8*)&As[rA * 32 + cA + 8] = pack8(x2, x3);
        }
        // stage B: bf16 global_load_lds
#pragma unroll
        for (int i = 0; i < 2; ++i) {
            const int rgrp = i * 64 + wave * 16;
            const int gB = min(bn0 + rgrp + rl, N - 1);
            const unsigned short* gpb = Btw + (size_t)gB * 256 + k0 + c8;
            __builtin_amdgcn_global_load_lds(
                (const __attribute__((address_space(1))) void*)gpb,
                (__attribute__((address_space(3))) void*)(Bs + (size_t)rgrp * 32),
                16, 0, 0);
        }
        __syncthreads();

        bf16x8 af[4], bw[4];
#pragma unroll
        for (int t = 0; t < 4; ++t) {
            af[t] = *(const bf16x8*)&As[(wm * 64 + t * 16 + l16) * 32 + quad * 8];
            bw[t] = *(const bf16x8*)&Bs[(wn * 64 + t * 16 + l16) * 32 + quad * 8];
        }
#pragma unroll
        for (int tm = 0; tm < 4; ++tm)
#pragma unroll
            for (int tn = 0; tn < 4; ++tn)
                acc[tm][tn] = __builtin_amdgcn_mfma_f32_16x16x32_bf16(
                    af[tm], bw[tn], acc[tm][tn], 0, 0, 0);
    }

#pragma unroll
    for (int tm = 0; tm < 4; ++tm) {
        const int row0 = bm0 + wm * 64 + tm * 16 + quad * 4;
#pragma unroll
        for (int tn = 0; tn < 4; ++tn) {
            const int col = bn0 + wn * 64 + tn * 16 + l16;
            if (col < N) {
                const float bv = bias[col];
#pragma unroll
                for (int r = 0; r < 4; ++r) {
                    const int row = row0 + r;
                    if (row < M)
                        C[(size_t)row * ldc + col] = f2bf(acc[tm][tn][r] + bv);
                }
            }
        }
    }
}

// ---------------------------------------------------------------------------
// Deformable sampling: 1 thread per (query, head), 32 channels.
// Block 256 = 32 sorted queries x 8 heads. Grid 1256 (w-swizzled, 1250 used).
// ---------------------------------------------------------------------------
__global__ void __launch_bounds__(256)
msda_sample(const unsigned short* __restrict__ v,
            const unsigned short* __restrict__ oa,
            const float* __restrict__ rp,
            const int* __restrict__ perm,
            unsigned short* __restrict__ out) {
    const int b = blockIdx.x;
    const int w = (b & 7) * 157 + (b >> 3);
    if (w >= 1250) return;
    const int tid = threadIdx.x;
    const int qi = tid >> 3;
    const int h = tid & 7;
    const int q = perm[w * 32 + qi];

    const float rx = rp[q * 2 + 0] * (float)GW;
    const float ry = rp[q * 2 + 1] * (float)GH;

    const unsigned short* oaq = oa + (size_t)q * 144;
    float lg[NP];
    float mx = -1e30f;
#pragma unroll
    for (int p = 0; p < NP; ++p) {
        lg[p] = bf2f(oaq[96 + h * NP + p]);
        mx = fmaxf(mx, lg[p]);
    }
    float s = 0.0f;
#pragma unroll
    for (int p = 0; p < NP; ++p) { lg[p] = expf(lg[p] - mx); s += lg[p]; }
    const float inv = 1.0f / s;

    float acc[32] = {};
#pragma unroll
    for (int p = 0; p < NP; ++p) {
        const float aw = lg[p] * inv;
        const float lx = rx + bf2f(oaq[h * 12 + p * 2 + 0]) - 0.5f;
        const float ly = ry + bf2f(oaq[h * 12 + p * 2 + 1]) - 0.5f;
        const float fx0 = floorf(lx), fy0 = floorf(ly);
        const int x0 = (int)fx0, y0 = (int)fy0;
        const float fx = lx - fx0, fy = ly - fy0;
#pragma unroll
        for (int dy = 0; dy < 2; ++dy) {
            const int yi = y0 + dy;
            const float wyv = dy ? fy : 1.0f - fy;
#pragma unroll
            for (int dx = 0; dx < 2; ++dx) {
                const int xi = x0 + dx;
                const float wxv = dx ? fx : 1.0f - fx;
                const bool valid = (xi >= 0) & (xi < GW) & (yi >= 0) & (yi < GH);
                const int yc = min(max(yi, 0), GH - 1);
                const int xc = min(max(xi, 0), GW - 1);
                const float wgt = valid ? aw * wxv * wyv : 0.0f;
                const unsigned short* cell =
                    &v[((size_t)(yc * GW + xc)) * 256 + h * 32];
#pragma unroll
                for (int sl = 0; sl < 4; ++sl) {
                    const bf16x8 g = *(const bf16x8*)(cell + sl * 8);
#pragma unroll
                    for (int j = 0; j < 8; ++j)
                        acc[sl * 8 + j] += bf2f((unsigned short)g[j]) * wgt;
                }
            }
        }
    }
    unsigned short* op = &out[(size_t)q * 256 + h * 32];
#pragma unroll
    for (int sl = 0; sl < 4; ++sl) {
        bf16x8 o;
#pragma unroll
        for (int j = 0; j < 8; ++j) o[j] = (short)f2bf(acc[sl * 8 + j]);
        *(bf16x8*)(op + sl * 8) = o;
    }
}

extern "C" void kernel_launch(void* const* d_in, const int* in_sizes, int n_in,
                              void* d_out, int out_size, void* d_ws, size_t ws_size,
                              hipStream_t stream) {
    const float* query  = (const float*)d_in[0];
    const float* value  = (const float*)d_in[1];
    const float* rp     = (const float*)d_in[2];
    const float* W_off  = (const float*)d_in[5];
    const float* b_off  = (const float*)d_in[6];
    const float* W_attn = (const float*)d_in[7];
    const float* b_attn = (const float*)d_in[8];
    const float* W_val  = (const float*)d_in[9];
    const float* b_val  = (const float*)d_in[10];
    const float* W_out  = (const float*)d_in[11];
    const float* b_out  = (const float*)d_in[12];
    const float* ln1_g  = (const float*)d_in[13];
    const float* ln1_b  = (const float*)d_in[14];
    const float* W1     = (const float*)d_in[15];
    const float* b1     = (const float*)d_in[16];
    const float* W2     = (const float*)d_in[17];
    const float* b2     = (const float*)d_in[18];
    const float* ln2_g  = (const float*)d_in[19];
    const float* ln2_b  = (const float*)d_in[20];

    char* ws = (char*)d_ws;
    // layout (bytes), end 53,250,048:
    //  [0,        598016)   Bt (1168 x 256 bf16)
    //  [598016,   598592)   bias_oa
    //  [598592,   601600)   hist
    //  [601600,   604608)   cursor
    //  [604608,   764608)   perm
    //  [770048,   21250048) v_bf  -> y_bf  (v dead after sampling)
    //  [21250048, 32770048) oa_bf (dead after sampling)
    //  [32770048, 53250048) msda_bf -> h1_bf (msda dead after Wout GEMM)
    unsigned short* Bt      = (unsigned short*)ws;
    float*          bias_oa = (float*)(ws + 598016);
    int*            hist    = (int*)(ws + 598592);
    int*            cursor  = (int*)(ws + 601600);
    int*            perm    = (int*)(ws + 604608);
    unsigned short* v_bf    = (unsigned short*)(ws + 770048);
    unsigned short* y_bf    = v_bf;
    unsigned short* oa_bf   = (unsigned short*)(ws + 21250048);
    unsigned short* msda_bf = (unsigned short*)(ws + 32770048);
    unsigned short* h1_bf   = msda_bf;
    float*          outp    = (float*)d_out;

    dim3 blk(256);
    wtrans_kernel<<<dim3(4, 4, 6), blk, 0, stream>>>(W_val, W_off, W_attn, W_out, W1, W2,
                                                     b_off, b_attn, Bt, bias_oa, hist);
    sort_hist<<<dim3(157), blk, 0, stream>>>(rp, hist);
    sort_scan<<<dim3(1), dim3(64), 0, stream>>>(hist, cursor);
    sort_scatter<<<dim3(157), blk, 0, stream>>>(rp, cursor, perm);
    // v = value @ W_val + b_val -> bf16   (fp32 A staged in-kernel)
    gemm64<2, 1><<<dim3(625), blk, 0, stream>>>((const void*)value, Bt, b_val,
                                                nullptr, nullptr, nullptr,
                                                (void*)v_bf, NQ);
    // offattn = query @ [W_off|W_attn] + bias -> bf16 [NQ][144]
    gemm_bt<<<dim3(2, 313), blk, 0, stream>>>(query, Bt + 256 * 256, bias_oa,
                                              oa_bf, NQ, 144, 144);
    // sampling (sorted order) -> msda bf16
    msda_sample<<<dim3(1256), blk, 0, stream>>>(v_bf, oa_bf, rp, perm, msda_bf);
    // y = LN(msda @ W_out + b_out + query) -> bf16  (v_bf region now free)
    gemm64<3, 0><<<dim3(625), blk, 0, stream>>>((const void*)msda_bf, Bt + 400 * 256, b_out,
                                                (const void*)query, ln1_g, ln1_b,
                                                (void*)y_bf, NQ);
    // h1 = gelu(y @ W1 + b1) -> bf16   (msda region now free)
    gemm64<1, 0><<<dim3(625), blk, 0, stream>>>((const void*)y_bf, Bt + 656 * 256, b1,
                                                nullptr, nullptr, nullptr,
                                                (void*)h1_bf, NQ);
    // out = LN(h1 @ W2 + b2 + y) -> fp32
    gemm64<4, 0><<<dim3(625), blk, 0, stream>>>((const void*)h1_bf, Bt + 912 * 256, b2,
                                                (const void*)y_bf, ln2_g, ln2_b,
                                                (void*)outp, NQ);
}

// Round 6
// 334.519 us; speedup vs baseline: 1.2792x; 1.2792x over previous
//
#include <hip/hip_runtime.h>
#include <math.h>

#define NQ 40000
#define DIM 256
#define NH 8
#define NP 6
#define HD 32
#define GH 200
#define GW 200
#define TS 8
#define TNX 25
#define NT 625

typedef short bf16x8 __attribute__((ext_vector_type(8)));
typedef float f32x4 __attribute__((ext_vector_type(4)));

__device__ __forceinline__ unsigned short f2bf(float f) {
    unsigned int u = __builtin_bit_cast(unsigned int, f);
    u += 0x7fffu + ((u >> 16) & 1u);
    return (unsigned short)(u >> 16);
}
__device__ __forceinline__ float bf2f(unsigned short h) {
    return __builtin_bit_cast(float, ((unsigned int)h) << 16);
}

__device__ __forceinline__ int tile_of(const float* rp, int q) {
    const float rx = rp[q * 2 + 0] * (float)GW;
    const float ry = rp[q * 2 + 1] * (float)GH;
    const int tx = min(max((int)(rx * (1.0f / TS)), 0), TNX - 1);
    const int ty = min(max((int)(ry * (1.0f / TS)), 0), TNX - 1);
    return ty * TNX + tx;
}

// ---------------------------------------------------------------------------
// fp32 -> bf16 for query (blocks 0..4999) and value (5000..9999);
// blocks 10000..10156 run the sort histogram (hist pre-zeroed by wtrans).
// ---------------------------------------------------------------------------
__global__ void __launch_bounds__(256)
f2b_hist(const float* __restrict__ q, unsigned short* __restrict__ qd,
         const float* __restrict__ v, unsigned short* __restrict__ vd,
         const float* __restrict__ rp, int* __restrict__ hist) {
    int b = blockIdx.x;
    if (b >= 10000) {
        const int qq = (b - 10000) * 256 + threadIdx.x;
        if (qq < NQ) atomicAdd(&hist[tile_of(rp, qq)], 1);
        return;
    }
    const float* src; unsigned short* dst;
    if (b < 5000) { src = q; dst = qd; } else { src = v; dst = vd; b -= 5000; }
    const int i = b * 256 + threadIdx.x;
    const float4* s = (const float4*)src;
    float4 a = s[(size_t)i * 2], c = s[(size_t)i * 2 + 1];
    bf16x8 o;
    o[0] = (short)f2bf(a.x); o[1] = (short)f2bf(a.y);
    o[2] = (short)f2bf(a.z); o[3] = (short)f2bf(a.w);
    o[4] = (short)f2bf(c.x); o[5] = (short)f2bf(c.y);
    o[6] = (short)f2bf(c.z); o[7] = (short)f2bf(c.w);
    *(bf16x8*)(dst + (size_t)i * 8) = o;
}

// ---------------------------------------------------------------------------
// Weight prep: transpose K x N fp32 -> [N][K] bf16 rows into Bt.
// Row offsets: Wval 0, Woff 256, Wattn 352, Wout 400, W1 656, W2 912.
// Also zeroes the sort histogram and packs bias_oa.
// ---------------------------------------------------------------------------
__global__ void __launch_bounds__(256)
wtrans_kernel(const float* __restrict__ Wval, const float* __restrict__ Woff,
              const float* __restrict__ Wattn, const float* __restrict__ Wout,
              const float* __restrict__ W1, const float* __restrict__ W2,
              const float* __restrict__ b_off, const float* __restrict__ b_attn,
              unsigned short* __restrict__ Bt, float* __restrict__ bias_oa,
              int* __restrict__ hist) {
    __shared__ float T[64][65];
    const int m = blockIdx.z;
    const float* src; int N; int dr0;
    if (m == 0)      { src = Wval;  N = 256; dr0 = 0; }
    else if (m == 1) { src = Woff;  N = 96;  dr0 = 256; }
    else if (m == 2) { src = Wattn; N = 48;  dr0 = 352; }
    else if (m == 3) { src = Wout;  N = 256; dr0 = 400; }
    else if (m == 4) { src = W1;    N = 256; dr0 = 656; }
    else             { src = W2;    N = 256; dr0 = 912; }

    if (m == 1 && blockIdx.x == 0 && blockIdx.y == 0 && threadIdx.x < 144)
        bias_oa[threadIdx.x] = threadIdx.x < 96 ? b_off[threadIdx.x]
                                                : b_attn[threadIdx.x - 96];
    if (m == 0 && blockIdx.y == 0) {
        const int i = blockIdx.x * 256 + threadIdx.x;
        if (i < NT) hist[i] = 0;
    }

    const int n0 = blockIdx.x * 64, k0 = blockIdx.y * 64;
    if (n0 >= N) return;
    const int col = threadIdx.x & 63, rg = threadIdx.x >> 6;
#pragma unroll
    for (int i = 0; i < 16; ++i) {
        const int r = rg + 4 * i;
        T[r][col] = (n0 + col < N) ? src[(size_t)(k0 + r) * N + n0 + col] : 0.0f;
    }
    __syncthreads();
#pragma unroll
    for (int i = 0; i < 16; ++i) {
        const int nl = rg + 4 * i;
        if (n0 + nl < N)
            Bt[(size_t)(dr0 + n0 + nl) * 256 + k0 + col] = f2bf(T[col][nl]);
    }
}

__global__ void __launch_bounds__(64)
sort_scan(const int* __restrict__ hist, int* __restrict__ cursor) {
    const int lane = threadIdx.x;
    int loc[10]; int t = 0;
#pragma unroll
    for (int j = 0; j < 10; ++j) {
        const int idx = lane * 10 + j;
        loc[j] = t;
        t += (idx < NT) ? hist[idx] : 0;
    }
    int s = t;
#pragma unroll
    for (int o = 1; o < 64; o <<= 1) {
        const int u = __shfl_up(s, o);
        if (lane >= o) s += u;
    }
    const int ex = s - t;
#pragma unroll
    for (int j = 0; j < 10; ++j) {
        const int idx = lane * 10 + j;
        if (idx < NT) cursor[idx] = ex + loc[j];
    }
}

__global__ void __launch_bounds__(256)
sort_scatter(const float* __restrict__ rp, int* __restrict__ cursor,
             int* __restrict__ perm) {
    const int q = blockIdx.x * 256 + threadIdx.x;
    if (q >= NQ) return;
    const int pos = atomicAdd(&cursor[tile_of(rp, q)], 1);
    perm[pos] = q;
}

// ---------------------------------------------------------------------------
// gemm64: C[M,256] = epi(A[M,256] @ Bt[256,256]^T + bias)
// BM=64, BN=256 (full row per block), BK=32, 4 waves, LDS double-buffer,
// pure-bf16 global_load_lds width-16 staging (R4-proven).
// EPI: 1 = exact-gelu -> bf16, 2 = bf16,
//      3 = LN(x + res_bf16) -> bf16, 4 = LN(x + res_bf16) -> fp32.
// M multiple of 64.
// ---------------------------------------------------------------------------
template <int EPI>
__global__ void __launch_bounds__(256)
gemm64(const unsigned short* __restrict__ A, const unsigned short* __restrict__ Btw,
       const float* __restrict__ bias, const unsigned short* __restrict__ res,
       const float* __restrict__ lng, const float* __restrict__ lnb,
       void* __restrict__ C, int M) {
    __shared__ __align__(16) unsigned short As[2][64 * 32];
    __shared__ __align__(16) unsigned short Bs[2][256 * 32];
    __shared__ __align__(16) float red[64][4][2];

    const int tid = threadIdx.x, lane = tid & 63, wave = tid >> 6;
    const int quad = lane >> 4, l16 = lane & 15;
    const int bm0 = blockIdx.x * 64;
    const int r16 = lane >> 2, ch = (lane & 3) * 8;

    f32x4 acc[4][4] = {};

    auto stage = [&](int kt, int buf) {
        const int k0 = kt * 32;
        {
            const unsigned short* gp =
                A + (size_t)(bm0 + wave * 16 + r16) * 256 + k0 + ch;
            __builtin_amdgcn_global_load_lds(
                (const __attribute__((address_space(1))) void*)gp,
                (__attribute__((address_space(3))) void*)(&As[buf][wave * 16 * 32]),
                16, 0, 0);
        }
#pragma unroll
        for (int j = 0; j < 4; ++j) {
            const int rowbase = (wave * 4 + j) * 16;
            const unsigned short* gp =
                Btw + (size_t)(rowbase + r16) * 256 + k0 + ch;
            __builtin_amdgcn_global_load_lds(
                (const __attribute__((address_space(1))) void*)gp,
                (__attribute__((address_space(3))) void*)(&Bs[buf][rowbase * 32]),
                16, 0, 0);
        }
    };

    stage(0, 0);
    __syncthreads();

    for (int kt = 0; kt < 8; ++kt) {
        const int cur = kt & 1;
        if (kt < 7) stage(kt + 1, 1 - cur);

        bf16x8 af[4], bw[4];
#pragma unroll
        for (int t = 0; t < 4; ++t) {
            af[t] = *(const bf16x8*)&As[cur][(t * 16 + l16) * 32 + quad * 8];
            bw[t] = *(const bf16x8*)&Bs[cur][(wave * 64 + t * 16 + l16) * 32 + quad * 8];
        }
#pragma unroll
        for (int tm = 0; tm < 4; ++tm)
#pragma unroll
            for (int tn = 0; tn < 4; ++tn)
                acc[tm][tn] = __builtin_amdgcn_mfma_f32_16x16x32_bf16(
                    af[tm], bw[tn], acc[tm][tn], 0, 0, 0);
        __syncthreads();
    }

    // --- epilogue. C/D layout: col = lane&15, row = quad*4 + reg ---
    float bias4[4];
#pragma unroll
    for (int tn = 0; tn < 4; ++tn) bias4[tn] = bias[wave * 64 + tn * 16 + l16];

    if (EPI == 1 || EPI == 2) {
#pragma unroll
        for (int tm = 0; tm < 4; ++tm) {
            const int row0 = bm0 + tm * 16 + quad * 4;
#pragma unroll
            for (int tn = 0; tn < 4; ++tn) {
                const int col = wave * 64 + tn * 16 + l16;
#pragma unroll
                for (int r = 0; r < 4; ++r) {
                    float x = acc[tm][tn][r] + bias4[tn];
                    if (EPI == 1) x = 0.5f * x * (1.0f + erff(x * 0.70710678118654752f));
                    ((unsigned short*)C)[(size_t)(row0 + r) * 256 + col] = f2bf(x);
                }
            }
        }
        return;
    }

    // LN variants: add bias + bf16 residual, then row stats over 256 cols.
#pragma unroll
    for (int tm = 0; tm < 4; ++tm) {
#pragma unroll
        for (int r = 0; r < 4; ++r) {
            const size_t rb = (size_t)(bm0 + tm * 16 + quad * 4 + r) * 256;
#pragma unroll
            for (int tn = 0; tn < 4; ++tn) {
                const int col = wave * 64 + tn * 16 + l16;
                acc[tm][tn][r] += bias4[tn] + bf2f(res[rb + col]);
            }
        }
    }
#pragma unroll
    for (int tm = 0; tm < 4; ++tm) {
#pragma unroll
        for (int r = 0; r < 4; ++r) {
            float s = 0.0f, sq = 0.0f;
#pragma unroll
            for (int tn = 0; tn < 4; ++tn) {
                const float e = acc[tm][tn][r];
                s += e; sq += e * e;
            }
#pragma unroll
            for (int o = 1; o < 16; o <<= 1) {
                s += __shfl_xor(s, o);
                sq += __shfl_xor(sq, o);
            }
            if (l16 == 0) {
                const int row = tm * 16 + quad * 4 + r;
                red[row][wave][0] = s;
                red[row][wave][1] = sq;
            }
        }
    }
    __syncthreads();

    float gv[4], bvv[4];
#pragma unroll
    for (int tn = 0; tn < 4; ++tn) {
        const int col = wave * 64 + tn * 16 + l16;
        gv[tn] = lng[col];
        bvv[tn] = lnb[col];
    }
#pragma unroll
    for (int tm = 0; tm < 4; ++tm) {
#pragma unroll
        for (int r = 0; r < 4; ++r) {
            const int row = tm * 16 + quad * 4 + r;
            const float4 p0 = *(const float4*)&red[row][0][0];
            const float4 p1 = *(const float4*)&red[row][2][0];
            const float sum = p0.x + p0.z + p1.x + p1.z;
            const float sumsq = p0.y + p0.w + p1.y + p1.w;
            const float mean = sum * (1.0f / 256.0f);
            const float var = sumsq * (1.0f / 256.0f) - mean * mean;
            const float rstd = rsqrtf(var + 1e-5f);
            const size_t rb = (size_t)(bm0 + row) * 256;
#pragma unroll
            for (int tn = 0; tn < 4; ++tn) {
                const int col = wave * 64 + tn * 16 + l16;
                const float o = (acc[tm][tn][r] - mean) * rstd * gv[tn] + bvv[tn];
                if (EPI == 3) ((unsigned short*)C)[rb + col] = f2bf(o);
                else          ((float*)C)[rb + col] = o;
            }
        }
    }
}

// ---------------------------------------------------------------------------
// offattn GEMM (N=144): bf16 A + B via global_load_lds, 128x128 tile (R4).
// ---------------------------------------------------------------------------
__global__ void __launch_bounds__(256)
gemm_bt(const unsigned short* __restrict__ A, const unsigned short* __restrict__ Btw,
        const float* __restrict__ bias, unsigned short* __restrict__ C,
        int M, int N, int ldc) {
    __shared__ __align__(16) unsigned short As[128 * 32];
    __shared__ __align__(16) unsigned short Bs[128 * 32];

    const int tid = threadIdx.x, lane = tid & 63, wave = tid >> 6;
    const int quad = lane >> 4, l16 = lane & 15;
    const int wm = wave >> 1, wn = wave & 1;
    const int bm0 = blockIdx.y * 128, bn0 = blockIdx.x * 128;

    f32x4 acc[4][4] = {};
    const int rl = lane >> 2;
    const int c8 = (lane & 3) * 8;

    for (int kt = 0; kt < 8; ++kt) {
        const int k0 = kt * 32;
        __syncthreads();
#pragma unroll
        for (int i = 0; i < 2; ++i) {
            const int rgrp = i * 64 + wave * 16;
            const int gA = min(bm0 + rgrp + rl, M - 1);
            const unsigned short* gpa = A + (size_t)gA * 256 + k0 + c8;
            __builtin_amdgcn_global_load_lds(
                (const __attribute__((address_space(1))) void*)gpa,
                (__attribute__((address_space(3))) void*)(As + (size_t)rgrp * 32),
                16, 0, 0);
            const int gB = min(bn0 + rgrp + rl, N - 1);
            const unsigned short* gpb = Btw + (size_t)gB * 256 + k0 + c8;
            __builtin_amdgcn_global_load_lds(
                (const __attribute__((address_space(1))) void*)gpb,
                (__attribute__((address_space(3))) void*)(Bs + (size_t)rgrp * 32),
                16, 0, 0);
        }
        __syncthreads();

        bf16x8 af[4], bw[4];
#pragma unroll
        for (int t = 0; t < 4; ++t) {
            af[t] = *(const bf16x8*)&As[(wm * 64 + t * 16 + l16) * 32 + quad * 8];
            bw[t] = *(const bf16x8*)&Bs[(wn * 64 + t * 16 + l16) * 32 + quad * 8];
        }
#pragma unroll
        for (int tm = 0; tm < 4; ++tm)
#pragma unroll
            for (int tn = 0; tn < 4; ++tn)
                acc[tm][tn] = __builtin_amdgcn_mfma_f32_16x16x32_bf16(
                    af[tm], bw[tn], acc[tm][tn], 0, 0, 0);
    }

#pragma unroll
    for (int tm = 0; tm < 4; ++tm) {
        const int row0 = bm0 + wm * 64 + tm * 16 + quad * 4;
#pragma unroll
        for (int tn = 0; tn < 4; ++tn) {
            const int col = bn0 + wn * 64 + tn * 16 + l16;
            if (col < N) {
                const float bv = bias[col];
#pragma unroll
                for (int r = 0; r < 4; ++r) {
                    const int row = row0 + r;
                    if (row < M)
                        C[(size_t)row * ldc + col] = f2bf(acc[tm][tn][r] + bv);
                }
            }
        }
    }
}

// ---------------------------------------------------------------------------
// Deformable sampling: 4 threads per (query, head), 8 channels each.
// Block 256 = 8 sorted queries x 8 heads x 4 slices; XCD band swizzle.
// Inner loop: per point, compute all 4 corner weights/addrs, issue the 4
// independent 16B gathers, then FMA (max memory-level parallelism).
// ---------------------------------------------------------------------------
__global__ void __launch_bounds__(256)
msda_sample(const unsigned short* __restrict__ v,
            const unsigned short* __restrict__ oa,
            const float* __restrict__ rp,
            const int* __restrict__ perm,
            unsigned short* __restrict__ out) {
    const int b = blockIdx.x;
    const int w = (b & 7) * 625 + (b >> 3);
    const int tid = threadIdx.x;
    const int slot = tid >> 2;
    const int q = perm[w * 8 + (slot >> 3)];
    const int h = slot & 7;
    const int c0 = (tid & 3) * 8;

    const float rx = rp[q * 2 + 0] * (float)GW;
    const float ry = rp[q * 2 + 1] * (float)GH;

    const unsigned short* oaq = oa + (size_t)q * 144;
    float lg[NP];
    float mx = -1e30f;
#pragma unroll
    for (int p = 0; p < NP; ++p) {
        lg[p] = bf2f(oaq[96 + h * NP + p]);
        mx = fmaxf(mx, lg[p]);
    }
    float s = 0.0f;
#pragma unroll
    for (int p = 0; p < NP; ++p) { lg[p] = expf(lg[p] - mx); s += lg[p]; }
    const float inv = 1.0f / s;

    const unsigned short* vh = v + h * 32 + c0;
    float acc[8] = {};
#pragma unroll
    for (int p = 0; p < NP; ++p) {
        const float aw = lg[p] * inv;
        const float lx = rx + bf2f(oaq[h * 12 + p * 2 + 0]) - 0.5f;
        const float ly = ry + bf2f(oaq[h * 12 + p * 2 + 1]) - 0.5f;
        const float fx0 = floorf(lx), fy0 = floorf(ly);
        const int x0 = (int)fx0, y0 = (int)fy0;
        const float fx = lx - fx0, fy = ly - fy0;

        const float wx0 = ((x0 >= 0) & (x0 < GW)) ? (1.0f - fx) : 0.0f;
        const float wx1 = ((x0 + 1 >= 0) & (x0 + 1 < GW)) ? fx : 0.0f;
        const float wy0 = ((y0 >= 0) & (y0 < GH)) ? (1.0f - fy) : 0.0f;
        const float wy1 = ((y0 + 1 >= 0) & (y0 + 1 < GH)) ? fy : 0.0f;
        const float w00 = aw * wx0 * wy0, w01 = aw * wx1 * wy0;
        const float w10 = aw * wx0 * wy1, w11 = aw * wx1 * wy1;

        const int x0c = min(max(x0, 0), GW - 1);
        const int x1c = min(max(x0 + 1, 0), GW - 1);
        const int y0c = min(max(y0, 0), GH - 1);
        const int y1c = min(max(y0 + 1, 0), GH - 1);

        const bf16x8 g00 = *(const bf16x8*)(vh + (size_t)(y0c * GW + x0c) * 256);
        const bf16x8 g01 = *(const bf16x8*)(vh + (size_t)(y0c * GW + x1c) * 256);
        const bf16x8 g10 = *(const bf16x8*)(vh + (size_t)(y1c * GW + x0c) * 256);
        const bf16x8 g11 = *(const bf16x8*)(vh + (size_t)(y1c * GW + x1c) * 256);

#pragma unroll
        for (int j = 0; j < 8; ++j) {
            acc[j] += bf2f((unsigned short)g00[j]) * w00
                    + bf2f((unsigned short)g01[j]) * w01
                    + bf2f((unsigned short)g10[j]) * w10
                    + bf2f((unsigned short)g11[j]) * w11;
        }
    }
    bf16x8 o;
#pragma unroll
    for (int j = 0; j < 8; ++j) o[j] = (short)f2bf(acc[j]);
    *(bf16x8*)&out[(size_t)q * 256 + h * 32 + c0] = o;
}

extern "C" void kernel_launch(void* const* d_in, const int* in_sizes, int n_in,
                              void* d_out, int out_size, void* d_ws, size_t ws_size,
                              hipStream_t stream) {
    const float* query  = (const float*)d_in[0];
    const float* value  = (const float*)d_in[1];
    const float* rp     = (const float*)d_in[2];
    const float* W_off  = (const float*)d_in[5];
    const float* b_off  = (const float*)d_in[6];
    const float* W_attn = (const float*)d_in[7];
    const float* b_attn = (const float*)d_in[8];
    const float* W_val  = (const float*)d_in[9];
    const float* b_val  = (const float*)d_in[10];
    const float* W_out  = (const float*)d_in[11];
    const float* b_out  = (const float*)d_in[12];
    const float* ln1_g  = (const float*)d_in[13];
    const float* ln1_b  = (const float*)d_in[14];
    const float* W1     = (const float*)d_in[15];
    const float* b1     = (const float*)d_in[16];
    const float* W2     = (const float*)d_in[17];
    const float* b2     = (const float*)d_in[18];
    const float* ln2_g  = (const float*)d_in[19];
    const float* ln2_b  = (const float*)d_in[20];

    char* ws = (char*)d_ws;
    // layout (bytes), end 73,730,048:
    //  [0,        598016)   Bt (1168 x 256 bf16)
    //  [598016,   598592)   bias_oa
    //  [598592,   601600)   hist
    //  [601600,   604608)   cursor
    //  [604608,   764608)   perm
    //  [770048,   21250048) query_bf -> h1_bf (query dead after LN1 GEMM)
    //  [21250048, 41730048) value_bf -> msda_bf (value dead after Wval GEMM)
    //  [41730048, 62210048) v_bf -> y_bf (v dead after sampling)
    //  [62210048, 73730048) oa_bf (dead after sampling)
    unsigned short* Bt       = (unsigned short*)ws;
    float*          bias_oa  = (float*)(ws + 598016);
    int*            hist     = (int*)(ws + 598592);
    int*            cursor   = (int*)(ws + 601600);
    int*            perm     = (int*)(ws + 604608);
    unsigned short* query_bf = (unsigned short*)(ws + 770048);
    unsigned short* h1_bf    = query_bf;
    unsigned short* value_bf = (unsigned short*)(ws + 21250048);
    unsigned short* msda_bf  = value_bf;
    unsigned short* v_bf     = (unsigned short*)(ws + 41730048);
    unsigned short* y_bf     = v_bf;
    unsigned short* oa_bf    = (unsigned short*)(ws + 62210048);
    float*          outp     = (float*)d_out;

    dim3 blk(256);
    // wtrans also zeroes hist (must precede f2b_hist)
    wtrans_kernel<<<dim3(4, 4, 6), blk, 0, stream>>>(W_val, W_off, W_attn, W_out, W1, W2,
                                                     b_off, b_attn, Bt, bias_oa, hist);
    f2b_hist<<<dim3(10157), blk, 0, stream>>>(query, query_bf, value, value_bf, rp, hist);
    sort_scan<<<dim3(1), dim3(64), 0, stream>>>(hist, cursor);
    sort_scatter<<<dim3(157), blk, 0, stream>>>(rp, cursor, perm);
    // v = value @ W_val + b_val -> bf16
    gemm64<2><<<dim3(625), blk, 0, stream>>>(value_bf, Bt, b_val,
                                             nullptr, nullptr, nullptr,
                                             (void*)v_bf, NQ);
    // offattn = query @ [W_off|W_attn] + bias -> bf16 [NQ][144]
    gemm_bt<<<dim3(2, 313), blk, 0, stream>>>(query_bf, Bt + 256 * 256, bias_oa,
                                              oa_bf, NQ, 144, 144);
    // sampling (sorted order) -> msda bf16
    msda_sample<<<dim3(5000), blk, 0, stream>>>(v_bf, oa_bf, rp, perm, msda_bf);
    // y = LN(msda @ W_out + b_out + query_bf) -> bf16  (v_bf region now free)
    gemm64<3><<<dim3(625), blk, 0, stream>>>(msda_bf, Bt + 400 * 256, b_out,
                                             query_bf, ln1_g, ln1_b,
                                             (void*)y_bf, NQ);
    // h1 = gelu(y @ W1 + b1) -> bf16   (query_bf region now free)
    gemm64<1><<<dim3(625), blk, 0, stream>>>(y_bf, Bt + 656 * 256, b1,
                                             nullptr, nullptr, nullptr,
                                             (void*)h1_bf, NQ);
    // out = LN(h1 @ W2 + b2 + y_bf) -> fp32
    gemm64<4><<<dim3(625), blk, 0, stream>>>(h1_bf, Bt + 912 * 256, b2,
                                             y_bf, ln2_g, ln2_b,
                                             (void*)outp, NQ);
}